// Round 16
// baseline (260.653 us; speedup 1.0000x reference)
//
#include <hip/hip_runtime.h>
#include <hip/hip_bf16.h>

#define EMB 64
#define XCOLS 20
#define NSYMP 15
#define BSH 7
#define BSZ 128          // nodes per bucket (1<<BSH)
#define MAXNB 1024       // supports N <= 131072
#define PCHUNK 4096
#define TROWS 51         // 4 birth + 2 gender + 45 symp rows

typedef float sf16 __attribute__((ext_vector_type(16)));

// ---------------- table transform (+ zero bcount for the CSR chain) ----------
__global__ void transform_kernel(const float* __restrict__ bt,
                                 const float* __restrict__ gt,
                                 const float* __restrict__ st,
                                 const float* __restrict__ Wl,
                                 const float* __restrict__ Wr,
                                 float* __restrict__ tL, float* __restrict__ tR,
                                 int* __restrict__ bcount) {
    __shared__ float row[EMB];
    int r = blockIdx.x;          // 0..50
    int d = threadIdx.x;         // 64 threads
    int gidx = blockIdx.x * 64 + threadIdx.x;
    if (gidx < MAXNB) bcount[gidx] = 0;      // folded zero_kernel
    const float* src = (r < 4) ? (bt + r * EMB)
                     : (r < 6) ? (gt + (r - 4) * EMB)
                               : (st + (r - 6) * EMB);
    row[d] = src[d];
    __syncthreads();
    float aL = 0.f, aR = 0.f;
#pragma unroll
    for (int k = 0; k < EMB; ++k) {
        float h = row[k];
        aL = fmaf(h, Wl[k * EMB + d], aL);
        aR = fmaf(h, Wr[k * EMB + d], aR);
    }
    tL[r * EMB + d] = aL;
    tR[r * EMB + d] = aR;
}

// ---------------- fused embed+GEMM1 via transformed tables ----------------
__global__ void embedgemm_kernel(const int* __restrict__ x,
                                 const float* __restrict__ tL,
                                 const float* __restrict__ tR,
                                 const float* __restrict__ bl,
                                 const float* __restrict__ br,
                                 float* __restrict__ outL, float* __restrict__ outR,
                                 int N) {
    __shared__ int xs[4 * XCOLS];
    int node = blockIdx.x * 4 + (threadIdx.x >> 6);
    int d = threadIdx.x & 63;
    if (threadIdx.x < 4 * XCOLS) {
        int n2 = blockIdx.x * 4 + threadIdx.x / XCOLS;
        int c = threadIdx.x % XCOLS;
        xs[threadIdx.x] = (n2 < N) ? x[n2 * XCOLS + c] : 0;
    }
    __syncthreads();
    if (node >= N) return;
    const int* xr = &xs[(threadIdx.x >> 6) * XCOLS];
    int rbi = xr[1] + 2 * xr[2] + 3 * xr[3];   // birth row 0..3
    int rg = 4 + xr[4];                        // gender row 4..5
    float fL = 0.f, fR = 0.f;
#pragma unroll
    for (int j = 0; j < NSYMP; ++j) {
        int row = 6 + j * 3 + xr[5 + j];
        fL += tL[row * EMB + d];
        fR += tR[row * EMB + d];
    }
    float aL = (tL[rbi * EMB + d] + tL[rg * EMB + d] + fL * (1.f / 15.f)) * (1.f / 3.f) + bl[d];
    float aR = (tR[rbi * EMB + d] + tR[rg * EMB + d] + fR * (1.f / 15.f)) * (1.f / 3.f) + br[d];
    outL[node * EMB + d] = aL;
    outR[node * EMB + d] = aR;
}

// ---------------- dual GEMM v8: scalar-cache h broadcast + register weights --
// v6 was LDS-pipe-bound: 16 uniform ds_read_b128/node deliver 16B/instr on a
// 1024B/instr pipe (~31us of pure LDS time). v8 pulls the wave-uniform h row
// through the SCALAR path instead: 4 x s_load_dwordx16 into 64 SGPRs (volatile
// asm, in-order), s_waitcnt lgkmcnt(0) + sched_barrier(0) (rule #18: hipcc
// hoists reg-only ops past inline-asm waitcnt), then 128 v_fma with SGPR
// broadcast operands (1 SGPR/VALU instr - legal). No LDS, no barriers.
__global__ __launch_bounds__(256, 3)
void gemm_dual_kernel(const float* __restrict__ h,
                      const float* __restrict__ Wl, const float* __restrict__ bl,
                      const float* __restrict__ Wr, const float* __restrict__ br,
                      float* __restrict__ outL, float* __restrict__ outR, int N) {
    int lane = threadIdx.x & 63;
    int wv = threadIdx.x >> 6;
    float wl[EMB], wr[EMB];
#pragma unroll
    for (int k = 0; k < EMB; ++k) {
        wl[k] = Wl[k * EMB + lane];
        wr[k] = Wr[k * EMB + lane];
    }
    float blv = bl[lane], brv = br[lane];
    int stride = gridDim.x * 4;
    for (int node = blockIdx.x * 4 + wv; node < N; node += stride) {
        int un = __builtin_amdgcn_readfirstlane(node);
        const float* hrow = h + (size_t)un * EMB;
        sf16 va, vb, vc, vd;
        asm volatile("s_load_dwordx16 %0, %1, 0x0"  : "=s"(va) : "s"(hrow));
        asm volatile("s_load_dwordx16 %0, %1, 0x40" : "=s"(vb) : "s"(hrow));
        asm volatile("s_load_dwordx16 %0, %1, 0x80" : "=s"(vc) : "s"(hrow));
        asm volatile("s_load_dwordx16 %0, %1, 0xc0" : "=s"(vd) : "s"(hrow));
        asm volatile("s_waitcnt lgkmcnt(0)" ::: "memory");
        __builtin_amdgcn_sched_barrier(0);
        float l0 = blv, l1 = 0.f, r0 = brv, r1 = 0.f;
#pragma unroll
        for (int k = 0; k < 16; ++k) {
            l0 = fmaf(va[k], wl[k], l0);
            r0 = fmaf(va[k], wr[k], r0);
            l1 = fmaf(vb[k], wl[16 + k], l1);
            r1 = fmaf(vb[k], wr[16 + k], r1);
            l0 = fmaf(vc[k], wl[32 + k], l0);
            r0 = fmaf(vc[k], wr[32 + k], r0);
            l1 = fmaf(vd[k], wl[48 + k], l1);
            r1 = fmaf(vd[k], wr[48 + k], r1);
        }
        outL[(size_t)node * EMB + lane] = l0 + l1;
        outR[(size_t)node * EMB + lane] = r0 + r1;
    }
}

// ---------------- CSR build via 2-level radix partition ----------------
__global__ void bincount_kernel(const int* __restrict__ ei, int* __restrict__ bcount,
                                int* __restrict__ offs, int E, int NB, int N) {
    __shared__ int lh[MAXNB];
    for (int j = threadIdx.x; j < NB; j += 256) lh[j] = 0;
    __syncthreads();
    for (int i = blockIdx.x * 256 + threadIdx.x; i < E; i += gridDim.x * 256)
        atomicAdd(&lh[ei[E + i] >> BSH], 1);
    __syncthreads();
    for (int j = threadIdx.x; j < NB; j += 256)
        if (lh[j]) atomicAdd(&bcount[j], lh[j]);
    if (blockIdx.x == 0 && threadIdx.x == 0) offs[N] = E + N;   // slots incl. selfs
}

__global__ void bscan_kernel(const int* __restrict__ bcount, int* __restrict__ boffs,
                             int* __restrict__ bcursor, int NB) {
    __shared__ int s[1024];
    int t = threadIdx.x;
    int v0 = (t < NB) ? bcount[t] : 0;
    s[t] = v0;
    __syncthreads();
    for (int off = 1; off < 1024; off <<= 1) {
        int v = (t >= off) ? s[t - off] : 0;
        __syncthreads();
        s[t] += v;
        __syncthreads();
    }
    if (t < NB) {
        boffs[t + 1] = s[t];
        bcursor[t] = s[t] - v0;
    }
    if (t == 0) boffs[0] = 0;
}

__global__ void partition_kernel(const int* __restrict__ ei, int* __restrict__ bcursor,
                                 int* __restrict__ epart, int E, int NB) {
    __shared__ int lh[MAXNB];
    for (int j = threadIdx.x; j < NB; j += 256) lh[j] = 0;
    __syncthreads();
    int base = blockIdx.x * PCHUNK;
    int end = min(E, base + PCHUNK);
    for (int i = base + threadIdx.x; i < end; i += 256)
        atomicAdd(&lh[ei[E + i] >> BSH], 1);
    __syncthreads();
    for (int j = threadIdx.x; j < NB; j += 256) {
        int c = lh[j];
        lh[j] = c ? atomicAdd(&bcursor[j], c) : 0;
    }
    __syncthreads();
    for (int i = base + threadIdx.x; i < end; i += 256) {
        int dst = ei[E + i];
        int src = ei[i];
        int slot = atomicAdd(&lh[dst >> BSH], 1);
        epart[slot] = (src << BSH) | (dst & (BSZ - 1));
    }
}

// finalize: per-wave sub-histograms; node n gets deg+1 slots, slot 0 = self.
__global__ void finalize_kernel(const int* __restrict__ epart, const int* __restrict__ boffs,
                                int* __restrict__ offs, int* __restrict__ ssrc, int N) {
    __shared__ int deg4[4][BSZ];
    __shared__ int pos[BSZ];
    __shared__ int cur4[4][BSZ];
    int b = blockIdx.x;
    int t = threadIdx.x;
    int w = t >> 6;
    int n0 = b << BSH;
    int r0 = boffs[b], r1 = boffs[b + 1];
    ((int*)deg4)[t] = 0;
    ((int*)deg4)[t + 256] = 0;
    __syncthreads();
    for (int e = r0 + t; e < r1; e += 256)
        atomicAdd(&deg4[w][epart[e] & (BSZ - 1)], 1);
    __syncthreads();
    int d0 = 0, d1 = 0, d2 = 0, sum = 0;
    if (t < BSZ) {
        d0 = deg4[0][t]; d1 = deg4[1][t]; d2 = deg4[2][t];
        sum = d0 + d1 + d2 + deg4[3][t];
        pos[t] = sum;
    }
    __syncthreads();
    for (int off = 1; off < BSZ; off <<= 1) {
        int v = (t < BSZ && t >= off) ? pos[t - off] : 0;
        __syncthreads();
        if (t < BSZ) pos[t] += v;
        __syncthreads();
    }
    if (t < BSZ) {
        int node = n0 + t;
        int base = r0 + n0 + (pos[t] - sum) + t;   // edges + self-slots before node
        if (node < N) {
            offs[node] = base;
            ssrc[base] = node;                     // self-loop at slot 0
        }
        cur4[0][t] = base + 1;
        cur4[1][t] = base + 1 + d0;
        cur4[2][t] = base + 1 + d0 + d1;
        cur4[3][t] = base + 1 + d0 + d1 + d2;
    }
    __syncthreads();
    for (int e = r0 + t; e < r1; e += 256) {
        int v = epart[e];
        int s = atomicAdd(&cur4[w][v & (BSZ - 1)], 1);
        ssrc[s] = v >> BSH;
    }
}

// ---------------- DPP cross-lane add (VALU pipe; compiler handles hazards) --
template <int CTRL>
__device__ __forceinline__ float dpp_add(float v) {
    union { float f; int i; } u, r;
    u.f = v;
    r.i = __builtin_amdgcn_update_dpp(0, u.i, CTRL, 0xF, 0xF, true);
    return v + r.f;
}

// ---------------- GATv2 layer: 16 edges per wave iteration, pipelined -------
// Self-loop is a real CSR edge (finalize inserts it). 4 dwordx4 gathers in
// flight per iteration (R15: 2-deep was co-bound, VALU 77% / 3.6 TB/s).
template <int L>
__global__ void gat_kernel(const float* __restrict__ xl, const float* __restrict__ xr,
                           const int* __restrict__ offs, const int* __restrict__ ssrc,
                           const float* __restrict__ att, const float* __restrict__ bias,
                           const float* __restrict__ linW, const float* __restrict__ linb,
                           float* __restrict__ out, int N) {
    int wid = blockIdx.x * 4 + (threadIdx.x >> 6);
    int lane = threadIdx.x & 63;
    if (wid >= N) return;
    int grp = lane >> 4;          // edge slot within each 4-wide batch
    int li = lane & 15;           // float4 channel slot
    unsigned cb = (unsigned)li << 2;

    const float LOG2E = 1.4426950408889634f;
    float4 att4 = *(const float4*)(att + cb);
    att4.x *= LOG2E; att4.y *= LOG2E; att4.z *= LOG2E; att4.w *= LOG2E;
    float4 bias4 = *(const float4*)(bias + cb);
    unsigned rb = (unsigned)wid << 6;
    float4 xr4 = *(const float4*)(xr + rb + cb);

    int e0 = offs[wid], e1 = offs[wid + 1];

    float s = 0.f;
    float4 acc = {0.f, 0.f, 0.f, 0.f};

    // prologue: indices for first 16-edge batch (ssrc padded -> uncond loads OK)
    unsigned sA = (unsigned)ssrc[e0 + grp];
    unsigned sB = (unsigned)ssrc[e0 + 4 + grp];
    unsigned sC = (unsigned)ssrc[e0 + 8 + grp];
    unsigned sD = (unsigned)ssrc[e0 + 12 + grp];
    sA = (e0 + grp < e1) ? sA : (unsigned)wid;
    sB = (e0 + 4 + grp < e1) ? sB : (unsigned)wid;
    sC = (e0 + 8 + grp < e1) ? sC : (unsigned)wid;
    sD = (e0 + 12 + grp < e1) ? sD : (unsigned)wid;

    for (int t = e0; t < e1; t += 16) {
        float4 a = *(const float4*)(xl + (sA << 6) + cb);
        float4 b = *(const float4*)(xl + (sB << 6) + cb);
        float4 c = *(const float4*)(xl + (sC << 6) + cb);
        float4 dd = *(const float4*)(xl + (sD << 6) + cb);
        int tn = t + 16;
        unsigned nA = (unsigned)ssrc[tn + grp];
        unsigned nB = (unsigned)ssrc[tn + 4 + grp];
        unsigned nC = (unsigned)ssrc[tn + 8 + grp];
        unsigned nD = (unsigned)ssrc[tn + 12 + grp];
        nA = (tn + grp < e1) ? nA : (unsigned)wid;
        nB = (tn + 4 + grp < e1) ? nB : (unsigned)wid;
        nC = (tn + 8 + grp < e1) ? nC : (unsigned)wid;
        nD = (tn + 12 + grp < e1) ? nD : (unsigned)wid;
        bool vA = t + grp < e1;
        bool vB = t + 4 + grp < e1;
        bool vC = t + 8 + grp < e1;
        bool vD = t + 12 + grp < e1;

        float ux, uy, uz, uw, pa;

        ux = a.x + xr4.x; ux = fmaxf(ux, 0.2f * ux);
        uy = a.y + xr4.y; uy = fmaxf(uy, 0.2f * uy);
        uz = a.z + xr4.z; uz = fmaxf(uz, 0.2f * uz);
        uw = a.w + xr4.w; uw = fmaxf(uw, 0.2f * uw);
        pa = att4.x * ux + att4.y * uy + att4.z * uz + att4.w * uw;
        pa = dpp_add<0xB1>(pa);
        pa = dpp_add<0x4E>(pa);
        if (L == 2) { pa = dpp_add<0x141>(pa); pa = dpp_add<0x140>(pa); }
        float pA = exp2f(pa);
        pA = vA ? pA : 0.f;
        s += pA;
        acc.x += pA * a.x; acc.y += pA * a.y; acc.z += pA * a.z; acc.w += pA * a.w;

        ux = b.x + xr4.x; ux = fmaxf(ux, 0.2f * ux);
        uy = b.y + xr4.y; uy = fmaxf(uy, 0.2f * uy);
        uz = b.z + xr4.z; uz = fmaxf(uz, 0.2f * uz);
        uw = b.w + xr4.w; uw = fmaxf(uw, 0.2f * uw);
        pa = att4.x * ux + att4.y * uy + att4.z * uz + att4.w * uw;
        pa = dpp_add<0xB1>(pa);
        pa = dpp_add<0x4E>(pa);
        if (L == 2) { pa = dpp_add<0x141>(pa); pa = dpp_add<0x140>(pa); }
        float pB = exp2f(pa);
        pB = vB ? pB : 0.f;
        s += pB;
        acc.x += pB * b.x; acc.y += pB * b.y; acc.z += pB * b.z; acc.w += pB * b.w;

        ux = c.x + xr4.x; ux = fmaxf(ux, 0.2f * ux);
        uy = c.y + xr4.y; uy = fmaxf(uy, 0.2f * uy);
        uz = c.z + xr4.z; uz = fmaxf(uz, 0.2f * uz);
        uw = c.w + xr4.w; uw = fmaxf(uw, 0.2f * uw);
        pa = att4.x * ux + att4.y * uy + att4.z * uz + att4.w * uw;
        pa = dpp_add<0xB1>(pa);
        pa = dpp_add<0x4E>(pa);
        if (L == 2) { pa = dpp_add<0x141>(pa); pa = dpp_add<0x140>(pa); }
        float pC = exp2f(pa);
        pC = vC ? pC : 0.f;
        s += pC;
        acc.x += pC * c.x; acc.y += pC * c.y; acc.z += pC * c.z; acc.w += pC * c.w;

        ux = dd.x + xr4.x; ux = fmaxf(ux, 0.2f * ux);
        uy = dd.y + xr4.y; uy = fmaxf(uy, 0.2f * uy);
        uz = dd.z + xr4.z; uz = fmaxf(uz, 0.2f * uz);
        uw = dd.w + xr4.w; uw = fmaxf(uw, 0.2f * uw);
        pa = att4.x * ux + att4.y * uy + att4.z * uz + att4.w * uw;
        pa = dpp_add<0xB1>(pa);
        pa = dpp_add<0x4E>(pa);
        if (L == 2) { pa = dpp_add<0x141>(pa); pa = dpp_add<0x140>(pa); }
        float pD = exp2f(pa);
        pD = vD ? pD : 0.f;
        s += pD;
        acc.x += pD * dd.x; acc.y += pD * dd.y; acc.z += pD * dd.z; acc.w += pD * dd.w;

        sA = nA; sB = nB; sC = nC; sD = nD;
    }

    // combine the 4 edge groups (once per node)
    s += __shfl_xor(s, 16); s += __shfl_xor(s, 32);
    acc.x += __shfl_xor(acc.x, 16); acc.x += __shfl_xor(acc.x, 32);
    acc.y += __shfl_xor(acc.y, 16); acc.y += __shfl_xor(acc.y, 32);
    acc.z += __shfl_xor(acc.z, 16); acc.z += __shfl_xor(acc.z, 32);
    acc.w += __shfl_xor(acc.w, 16); acc.w += __shfl_xor(acc.w, 32);

    float inv = 1.f / (s + 1e-16f);
    if (L == 1) {
        float4 val;
        val.x = acc.x * inv + bias4.x;
        val.y = acc.y * inv + bias4.y;
        val.z = acc.z * inv + bias4.z;
        val.w = acc.w * inv + bias4.w;
        val.x = (val.x > 0.f) ? val.x : (__expf(val.x) - 1.f);
        val.y = (val.y > 0.f) ? val.y : (__expf(val.y) - 1.f);
        val.z = (val.z > 0.f) ? val.z : (__expf(val.z) - 1.f);
        val.w = (val.w > 0.f) ? val.w : (__expf(val.w) - 1.f);
        if (grp == 0) *(float4*)(out + rb + cb) = val;
    } else {
        float4 lw = *(const float4*)(linW + cb);
        float r = (acc.x * inv + bias4.x) * lw.x + (acc.y * inv + bias4.y) * lw.y +
                  (acc.z * inv + bias4.z) * lw.z + (acc.w * inv + bias4.w) * lw.w;
        r = dpp_add<0xB1>(r);
        r = dpp_add<0x4E>(r);
        r = dpp_add<0x141>(r);
        r = dpp_add<0x140>(r);
        if (lane == 0) out[wid] = r + linb[0];
    }
}

extern "C" void kernel_launch(void* const* d_in, const int* in_sizes, int n_in,
                              void* d_out, int out_size, void* d_ws, size_t ws_size,
                              hipStream_t stream) {
    const int* x = (const int*)d_in[0];
    const int* ei = (const int*)d_in[1];          // int32 marshalled
    const float* birth_tab = (const float*)d_in[2];
    const float* gender_tab = (const float*)d_in[3];
    const float* symp_tab = (const float*)d_in[4];
    const float* Wl1 = (const float*)d_in[5];
    const float* bl1 = (const float*)d_in[6];
    const float* Wr1 = (const float*)d_in[7];
    const float* br1 = (const float*)d_in[8];
    const float* att1 = (const float*)d_in[9];
    const float* bias1 = (const float*)d_in[10];
    const float* Wl2 = (const float*)d_in[11];
    const float* bl2 = (const float*)d_in[12];
    const float* Wr2 = (const float*)d_in[13];
    const float* br2 = (const float*)d_in[14];
    const float* att2 = (const float*)d_in[15];
    const float* bias2 = (const float*)d_in[16];
    const float* linW = (const float*)d_in[17];
    const float* linb = (const float*)d_in[18];
    float* outp = (float*)d_out;

    int N = in_sizes[0] / XCOLS;   // 100000
    int E = in_sizes[1] / 2;       // 1600000
    int NB = (N + BSZ - 1) >> BSH; // 782

    char* p = (char*)d_ws;
    auto alloc = [&](size_t bytes) {
        void* r = (void*)p;
        p += (bytes + 255) & ~(size_t)255;
        return r;
    };
    float* h0 = (float*)alloc((size_t)N * EMB * 4);
    float* bufA = (float*)alloc((size_t)N * EMB * 4);
    float* bufB = (float*)alloc((size_t)N * EMB * 4);
    int* bcount = (int*)alloc(MAXNB * 4);
    int* boffs = (int*)alloc((MAXNB + 1) * 4);
    int* bcursor = (int*)alloc(MAXNB * 4);
    int* offs = (int*)alloc((size_t)(N + 1) * 4);
    int* epart = (int*)alloc((size_t)E * 4);
    int* ssrc = (int*)alloc((size_t)(E + N + 128) * 4);  // edges + selfs + pad
    float* tL = (float*)alloc((size_t)TROWS * EMB * 4);
    float* tR = (float*)alloc((size_t)TROWS * EMB * 4);

    int ngrp = (N + 3) / 4;

    // transform first (also zeroes bcount for the CSR chain)
    transform_kernel<<<TROWS, 64, 0, stream>>>(birth_tab, gender_tab, symp_tab,
                                               Wl1, Wr1, tL, tR, bcount);
    // CSR build (2-level radix partition; self-loops added in finalize)
    bincount_kernel<<<512, 256, 0, stream>>>(ei, bcount, offs, E, NB, N);
    bscan_kernel<<<1, 1024, 0, stream>>>(bcount, boffs, bcursor, NB);
    partition_kernel<<<(E + PCHUNK - 1) / PCHUNK, 256, 0, stream>>>(ei, bcursor, epart, E, NB);
    finalize_kernel<<<NB, 256, 0, stream>>>(epart, boffs, offs, ssrc, N);

    // node pipeline
    embedgemm_kernel<<<ngrp, 256, 0, stream>>>(x, tL, tR, bl1, br1, bufA, bufB, N);
    gat_kernel<1><<<ngrp, 256, 0, stream>>>(bufA, bufB, offs, ssrc, att1, bias1,
                                            nullptr, nullptr, h0, N);
    gemm_dual_kernel<<<768, 256, 0, stream>>>(h0, Wl2, bl2, Wr2, br2, bufA, bufB, N);
    gat_kernel<2><<<ngrp, 256, 0, stream>>>(bufA, bufB, offs, ssrc, att2, bias2,
                                            linW, linb, outp, N);
}